// Round 7
// baseline (485.099 us; speedup 1.0000x reference)
//
#include <hip/hip_runtime.h>
#include <hip/hip_bf16.h>
#include <stdint.h>

typedef __attribute__((ext_vector_type(8))) short bf16x8;
typedef __attribute__((ext_vector_type(4))) float f32x4;

#define GLB(p) ((const __attribute__((address_space(1))) void*)(p))
#define LDSP(p) ((__attribute__((address_space(3))) void*)(p))

#define HW    3136
#define WIMG  56
#define PROW  58                 // padded row length (56 + 2 halo)
#define PNR   59                 // padded rows allocated
#define SIMG  (PNR * PROW)       // 3422 cells/image, 128 B each
#define C_IN  512

// RNE fp32 -> bf16
static __device__ __forceinline__ unsigned short f2bf(float f) {
    unsigned u = __builtin_bit_cast(unsigned, f);
    return (unsigned short)((u + 0x7FFFu + ((u >> 16) & 1u)) >> 16);
}

// ---------------- prep: weights -> bf16 (blocks 0..575) + s halo zero (576..607) ----
__global__ void prep_kernel(const float* __restrict__ wsq,
                            const float* __restrict__ w1,
                            const float* __restrict__ w3,
                            unsigned short* __restrict__ wsq_bf,
                            unsigned short* __restrict__ w1_bf,
                            unsigned short* __restrict__ w3r_bf,
                            unsigned short* __restrict__ s) {
    const int b = blockIdx.x, tid = threadIdx.x;
    if (b < 576) {
        int t = b * 256 + tid;
        if (t < 32768) wsq_bf[t] = f2bf(wsq[t]);
        if (t < 16384) w1_bf[t] = f2bf(w1[t]);
        int j = t >> 14, rem = t & 16383;
        int o = rem >> 6, c = rem & 63;
        w3r_bf[t] = f2bf(w3[(o * 64 + c) * 9 + j]);
    } else {
        // halo cells for e3 taps: padded row 0, padded row 57(+58 guard), cols {0,57}
        const int img = b - 576;
        uint4* sn = (uint4*)(s + (size_t)img * SIMG * 64);
        uint4 z; z.x = z.y = z.z = z.w = 0;
        for (int t = tid; t < 1824; t += 256) {              // 228 cells * 8 chunks
            int cell = t >> 3, q = t & 7;
            int row, col;
            if (cell < 116) { row = (cell >= 58) ? 57 : 0; col = cell % 58; }
            else { int c2 = cell - 116; row = 1 + (c2 >> 1); col = (c2 & 1) * 57; }
            sn[(size_t)(row * PROW + col) * 8 + q] = z;
        }
    }
}

// ---------------- squeeze: no LDS, no barriers ----------------
// grid (49, 32), block 256 (4 waves). Wave w owns cols [hw0+16w, +16), all 64 c_out.
// B-frag: 8 strided global f32 loads (16 lanes x 4B = 64B segments; sibling waves
// consume the other half of each 128B line). A-frags from L2-hot wsq_bf.
__global__ __launch_bounds__(256, 4) void squeeze_kernel(
    const float* __restrict__ x, const float* __restrict__ b_sq,
    const unsigned short* __restrict__ wsq_bf, unsigned short* __restrict__ s)
{
    const int n = blockIdx.y, hw0 = blockIdx.x * 64;
    const int tid = threadIdx.x;
    const int w = tid >> 6, l = tid & 63, lx = l & 15, lk = l >> 4;
    const int col = hw0 + w * 16 + lx;

    const float* xp = x + (size_t)n * C_IN * HW + col;
    const unsigned short* ap = wsq_bf + lx * C_IN + lk * 8;

    f32x4 acc[4] = {};
    for (int kb = 0; kb < 16; ++kb) {
        const int kbase = kb * 32 + lk * 8;
        float f[8];
        #pragma unroll
        for (int i = 0; i < 8; ++i) f[i] = xp[(size_t)(kbase + i) * HW];
        union { uint32_t u[4]; bf16x8 v; } bb;
        #pragma unroll
        for (int h = 0; h < 4; ++h)
            asm("v_cvt_pk_bf16_f32 %0, %1, %2" : "=v"(bb.u[h]) : "v"(f[2*h]), "v"(f[2*h+1]));
        bf16x8 a[4];
        #pragma unroll
        for (int mt = 0; mt < 4; ++mt)
            a[mt] = *(const bf16x8*)(ap + mt * 16 * C_IN + kb * 32);
        #pragma unroll
        for (int mt = 0; mt < 4; ++mt)
            acc[mt] = __builtin_amdgcn_mfma_f32_16x16x32_bf16(a[mt], bb.v, acc[mt], 0, 0, 0);
    }

    const int p = col + 59 + 2 * (col / WIMG);
    uint8_t* sn = (uint8_t*)s + (size_t)n * SIMG * 128 + (size_t)p * 128;
    const int psw = (p & 7) << 4;
    #pragma unroll
    for (int mt = 0; mt < 4; ++mt) {
        const int c0 = mt * 16 + lk * 4;
        float4 bias = *(const float4*)(b_sq + c0);
        const float* bp = (const float*)&bias;
        unsigned short v[4];
        #pragma unroll
        for (int r = 0; r < 4; ++r) v[r] = f2bf(fmaxf(acc[mt][r] + bp[r], 0.0f));
        uint2 pk;
        pk.x = (unsigned)v[0] | ((unsigned)v[1] << 16);
        pk.y = (unsigned)v[2] | ((unsigned)v[3] << 16);
        *(uint2*)(sn + ((c0 * 2) ^ psw)) = pk;
    }
}

// ---------------- expand: weights-in-VGPR, 7 tiles/block, reg-staged pipeline ----
// grid 896 = 32n x 4mt x 7tg (XCD-chunked: 896 = 8*112). Block 512 (8 waves).
// Wave (wm 0..3, wn 0..1): 16 c_out x 32 cols. Weight frags (2 e1 + 18 e3) loaded
// once per block into VGPRs. Per tile: ds_write staged regs -> tile, gload(next tile)
// -> regs (flies under compute), compute both branches, float4 stores.
__global__ __launch_bounds__(512, 2) void expand_kernel(
    const unsigned short* __restrict__ s,
    const unsigned short* __restrict__ w1_bf,
    const unsigned short* __restrict__ w3r_bf,
    const float* __restrict__ b1, const float* __restrict__ b3,
    float* __restrict__ out)
{
    __shared__ uint8_t tile[37120];                 // 5 padded rows x 58 cells x 128B
    const int bid = blockIdx.x;
    const int ord = (bid & 7) * 112 + (bid >> 3);   // XCD chunking (bijective)
    const int n  = ord / 28;
    const int r2 = ord - n * 28;
    const int mt = r2 / 7;
    const int tg = r2 - mt * 7;

    const int tid = threadIdx.x;
    const int w = tid >> 6, l = tid & 63, lx = l & 15, lk = l >> 4;
    const int wm = w >> 1, wn = w & 1;
    const int cb = mt * 64 + wm * 16;
    const int lk16 = lk * 16;

    // ---- preload weight fragments into VGPRs (live across the whole tile loop) ----
    bf16x8 w1f[2], w3f[9][2];
    #pragma unroll
    for (int k0 = 0; k0 < 2; ++k0)
        w1f[k0] = *(const bf16x8*)(w1_bf + (cb + lx) * 64 + k0 * 32 + lk * 8);
    #pragma unroll
    for (int j = 0; j < 9; ++j)
        #pragma unroll
        for (int k0 = 0; k0 < 2; ++k0)
            w3f[j][k0] = *(const bf16x8*)(w3r_bf + j * 16384 + (cb + lx) * 64 + k0 * 32 + lk * 8);

    const float bias1 = b1[cb + lx];
    const float bias3 = b3[cb + lx];
    const uint8_t* sn = (const uint8_t*)s + (size_t)n * SIMG * 128;
    float* outn = out + (size_t)n * 512 * HW;

    // ---- stage tile 0 into regs ----
    uint4 g[5];
    {
        const int y0 = (tg * 7 * 64) / WIMG;
        const uint8_t* src = sn + (size_t)y0 * PROW * 128;
        #pragma unroll
        for (int it = 0; it < 4; ++it)
            g[it] = *(const uint4*)(src + (size_t)(it * 512 + tid) * 16);
        if (tid < 272) g[4] = *(const uint4*)(src + (size_t)(2048 + tid) * 16);
    }

    for (int t = 0; t < 7; ++t) {
        const int ht  = tg * 7 + t;
        const int hw0 = ht * 64;
        const int cy0 = hw0 / WIMG;

        __syncthreads();                            // (a) all waves done reading tile
        #pragma unroll
        for (int it = 0; it < 4; ++it)
            *(uint4*)&tile[(it * 512 + tid) * 16] = g[it];
        if (tid < 272) *(uint4*)&tile[(2048 + tid) * 16] = g[4];
        __syncthreads();                            // (b) tile visible

        if (t < 6) {                                // stage next tile -> regs (async)
            const int ny0 = ((ht + 1) * 64) / WIMG;
            const uint8_t* src = sn + (size_t)ny0 * PROW * 128;
            #pragma unroll
            for (int it = 0; it < 4; ++it)
                g[it] = *(const uint4*)(src + (size_t)(it * 512 + tid) * 16);
            if (tid < 272) g[4] = *(const uint4*)(src + (size_t)(2048 + tid) * 16);
        }

        const int hb = hw0 + wn * 32;
        int pg[2], tb[2];
        #pragma unroll
        for (int nf = 0; nf < 2; ++nf) {
            int hw = hb + nf * 16 + lx;
            int p = hw + 59 + 2 * (hw / WIMG);
            pg[nf] = p;
            tb[nf] = (p - cy0 * PROW) * 128;
        }

        // ---- e1 ----
        {
            f32x4 acc[2] = {};
            #pragma unroll
            for (int k0 = 0; k0 < 2; ++k0) {
                bf16x8 av[2];
                #pragma unroll
                for (int nf = 0; nf < 2; ++nf)
                    av[nf] = *(const bf16x8*)&tile[tb[nf] + ((lk16 + k0 * 64) ^ ((pg[nf] & 7) << 4))];
                #pragma unroll
                for (int nf = 0; nf < 2; ++nf)
                    acc[nf] = __builtin_amdgcn_mfma_f32_16x16x32_bf16(av[nf], w1f[k0], acc[nf], 0, 0, 0);
            }
            float* op = outn + (size_t)(cb + lx) * HW + hb + lk * 4;
            #pragma unroll
            for (int nf = 0; nf < 2; ++nf) {
                float4 v;
                v.x = fmaxf(acc[nf][0] + bias1, 0.0f);
                v.y = fmaxf(acc[nf][1] + bias1, 0.0f);
                v.z = fmaxf(acc[nf][2] + bias1, 0.0f);
                v.w = fmaxf(acc[nf][3] + bias1, 0.0f);
                *(float4*)(op + nf * 16) = v;
            }
        }

        // ---- e3 (9 taps, halo zero => unconditional) ----
        {
            f32x4 acc[2] = {};
            #pragma unroll
            for (int j = 0; j < 9; ++j) {
                const int doff = (j / 3 - 1) * PROW + (j % 3 - 1);
                #pragma unroll
                for (int k0 = 0; k0 < 2; ++k0) {
                    bf16x8 av[2];
                    #pragma unroll
                    for (int nf = 0; nf < 2; ++nf) {
                        int pt = pg[nf] + doff;
                        av[nf] = *(const bf16x8*)&tile[tb[nf] + doff * 128 +
                                                      ((lk16 + k0 * 64) ^ ((pt & 7) << 4))];
                    }
                    #pragma unroll
                    for (int nf = 0; nf < 2; ++nf)
                        acc[nf] = __builtin_amdgcn_mfma_f32_16x16x32_bf16(av[nf], w3f[j][k0], acc[nf], 0, 0, 0);
                }
            }
            float* op = outn + (size_t)(256 + cb + lx) * HW + hb + lk * 4;
            #pragma unroll
            for (int nf = 0; nf < 2; ++nf) {
                float4 v;
                v.x = fmaxf(acc[nf][0] + bias3, 0.0f);
                v.y = fmaxf(acc[nf][1] + bias3, 0.0f);
                v.z = fmaxf(acc[nf][2] + bias3, 0.0f);
                v.w = fmaxf(acc[nf][3] + bias3, 0.0f);
                *(float4*)(op + nf * 16) = v;
            }
        }
    }
}

extern "C" void kernel_launch(void* const* d_in, const int* in_sizes, int n_in,
                              void* d_out, int out_size, void* d_ws, size_t ws_size,
                              hipStream_t stream) {
    const float* x   = (const float*)d_in[0];
    const float* wsq = (const float*)d_in[1];
    const float* bsq = (const float*)d_in[2];
    const float* w1  = (const float*)d_in[3];
    const float* b1  = (const float*)d_in[4];
    const float* w3  = (const float*)d_in[5];
    const float* b3  = (const float*)d_in[6];
    float* out = (float*)d_out;

    unsigned short* wsq_bf = (unsigned short*)d_ws;       // 32768 shorts
    unsigned short* w1_bf  = wsq_bf + 32768;              // 16384
    unsigned short* w3r_bf = w1_bf + 16384;               // 147456
    unsigned short* s      = w3r_bf + 147456;             // 32*3422*64 bf16 padded+swizzled

    prep_kernel<<<608, 256, 0, stream>>>(wsq, w1, w3, wsq_bf, w1_bf, w3r_bf, s);
    squeeze_kernel<<<dim3(49, 32), 256, 0, stream>>>(x, bsq, wsq_bf, s);
    expand_kernel<<<896, 512, 0, stream>>>(s, w1_bf, w3r_bf, b1, b3, out);
}

// Round 8
// 420.726 us; speedup vs baseline: 1.1530x; 1.1530x over previous
//
#include <hip/hip_runtime.h>
#include <hip/hip_bf16.h>
#include <stdint.h>

typedef __attribute__((ext_vector_type(8))) short bf16x8;
typedef __attribute__((ext_vector_type(4))) float f32x4;

#define GLB(p) ((const __attribute__((address_space(1))) void*)(p))
#define LDSP(p) ((__attribute__((address_space(3))) void*)(p))

#define HW    3136
#define WIMG  56
#define PROW  58                 // padded row length (56 + 2 halo)
#define PNR   59                 // padded rows allocated (58 used + 1 staging overread)
#define SIMG  (PNR * PROW)       // 3422 cells/image, 128 B each
#define C_IN  512

// RNE fp32 -> bf16
static __device__ __forceinline__ unsigned short f2bf(float f) {
    unsigned u = __builtin_bit_cast(unsigned, f);
    return (unsigned short)((u + 0x7FFFu + ((u >> 16) & 1u)) >> 16);
}

// ---------------- prep: weights -> bf16 (blocks 0..575) + s halo zero (576..607) ----
__global__ void prep_kernel(const float* __restrict__ wsq,
                            const float* __restrict__ w1,
                            const float* __restrict__ w3,
                            unsigned short* __restrict__ wsq_bf,
                            unsigned short* __restrict__ w1_bf,
                            unsigned short* __restrict__ w3r_bf,
                            unsigned short* __restrict__ s) {
    const int b = blockIdx.x, tid = threadIdx.x;
    if (b < 576) {
        int t = b * 256 + tid;
        if (t < 32768) wsq_bf[t] = f2bf(wsq[t]);
        if (t < 16384) w1_bf[t] = f2bf(w1[t]);
        int j = t >> 14, rem = t & 16383;
        int o = rem >> 6, c = rem & 63;
        w3r_bf[t] = f2bf(w3[(o * 64 + c) * 9 + j]);
    } else {
        // halo cells for e3 taps: padded row 0, padded row 57, cols {0,57} of rows 1..56
        const int img = b - 576;
        uint4* sn = (uint4*)(s + (size_t)img * SIMG * 64);
        uint4 z; z.x = z.y = z.z = z.w = 0;
        for (int t = tid; t < 1824; t += 256) {              // 228 cells * 8 chunks
            int cell = t >> 3, q = t & 7;
            int row, col;
            if (cell < 116) { row = (cell >= 58) ? 57 : 0; col = cell % 58; }
            else { int c2 = cell - 116; row = 1 + (c2 >> 1); col = (c2 & 1) * 57; }
            sn[(size_t)(row * PROW + col) * 8 + q] = z;
        }
    }
}

// ---------------- squeeze: dbuf global_load_lds staging, BK=64 ----------------
// grid (49, 32), block 256 (4 waves). Block: 64 out-ch x 64 cols, K=512, 8 K-steps.
// Wave w owns cols [hw0+16w,+16): per kc builds ONE B-frag (8 ds_read_b32 + 4 cvt_pk,
// swizzled 2-way banks = free), loads 4 A-frags from L1-hot wsq_bf, 4 MFMAs.
__global__ __launch_bounds__(256, 4) void squeeze_kernel(
    const float* __restrict__ x, const float* __restrict__ b_sq,
    const unsigned short* __restrict__ wsq_bf, unsigned short* __restrict__ s)
{
    __shared__ uint8_t xs[2][16384];                 // 64 ch x 64 col fp32, dbuf
    const int n = blockIdx.y, hw0 = blockIdx.x * 64;
    const int tid = threadIdx.x;
    const int w = tid >> 6, l = tid & 63, lx = l & 15, lk = l >> 4;

    const uint8_t* xbase = (const uint8_t*)(x + (size_t)n * C_IN * HW + hw0);

    auto stage = [&](int buf, int kb) {
        #pragma unroll
        for (int q = 0; q < 4; ++q) {
            int c = q * 256 + tid;            // 16B chunk 0..1023
            int r = c >> 4, g = c & 15;       // r: channel row 0..63 (coalesced 256B rows)
            const uint8_t* src = xbase + (size_t)(kb * 64 + r) * (HW * 4)
                                       + ((g * 16) ^ (((r >> 3) & 3) << 6));
            __builtin_amdgcn_global_load_lds(GLB(src), LDSP(&xs[buf][c * 16]), 16, 0, 0);
        }
    };

    stage(0, 0);
    __syncthreads();

    f32x4 acc[4] = {};
    const unsigned short* ap = wsq_bf + lx * C_IN + lk * 8;
    const int colb4 = (w * 16 + lx) * 4;
    const int swz = (lk & 3) << 6;

    for (int kb = 0; kb < 8; ++kb) {
        const int cur = kb & 1;
        if (kb < 7) stage(cur ^ 1, kb + 1);
        #pragma unroll
        for (int kc = 0; kc < 2; ++kc) {
            const uint8_t* bbase = &xs[cur][(kc * 32 + lk * 8) * 256 + (colb4 ^ swz)];
            float f[8];
            #pragma unroll
            for (int i = 0; i < 8; ++i) f[i] = *(const float*)(bbase + i * 256);
            union { uint32_t u[4]; bf16x8 v; } bb;
            #pragma unroll
            for (int h = 0; h < 4; ++h)
                asm("v_cvt_pk_bf16_f32 %0, %1, %2" : "=v"(bb.u[h]) : "v"(f[2*h]), "v"(f[2*h+1]));
            bf16x8 a[4];
            #pragma unroll
            for (int mt = 0; mt < 4; ++mt)
                a[mt] = *(const bf16x8*)(ap + mt * 16 * C_IN + kb * 64 + kc * 32);
            #pragma unroll
            for (int mt = 0; mt < 4; ++mt)
                acc[mt] = __builtin_amdgcn_mfma_f32_16x16x32_bf16(a[mt], bb.v, acc[mt], 0, 0, 0);
        }
        __syncthreads();
    }

    const int col = hw0 + w * 16 + lx;
    const int p = col + 59 + 2 * (col / WIMG);
    uint8_t* sn = (uint8_t*)s + (size_t)n * SIMG * 128 + (size_t)p * 128;
    const int psw = (p & 7) << 4;
    #pragma unroll
    for (int mt = 0; mt < 4; ++mt) {
        const int c0 = mt * 16 + lk * 4;
        float4 bias = *(const float4*)(b_sq + c0);
        const float* bp = (const float*)&bias;
        unsigned short v[4];
        #pragma unroll
        for (int r = 0; r < 4; ++r) v[r] = f2bf(fmaxf(acc[mt][r] + bp[r], 0.0f));
        uint2 pk;
        pk.x = (unsigned)v[0] | ((unsigned)v[1] << 16);
        pk.y = (unsigned)v[2] | ((unsigned)v[3] << 16);
        *(uint2*)(sn + ((c0 * 2) ^ psw)) = pk;
    }
}

// ---------------- expand: weights-in-VGPR (no spill), dbuf LDS tiles ----------------
// grid 896 = 32n x 4mt x 7tg (XCD-chunked bijective: 896 = 8*112). Block 512 (8 waves,
// launch_bounds(512,1) -> 256 VGPR/wave so the 80-VGPR weight set stays resident).
// Per tile: issue global_load_lds stage of t+1 into buf^1, compute t, one barrier.
__global__ __launch_bounds__(512, 1) void expand_kernel(
    const unsigned short* __restrict__ s,
    const unsigned short* __restrict__ w1_bf,
    const unsigned short* __restrict__ w3r_bf,
    const float* __restrict__ b1, const float* __restrict__ b3,
    float* __restrict__ out)
{
    __shared__ uint8_t tile[2][37120];              // 5 padded rows x 58 cells x 128B
    const int bid = blockIdx.x;
    const int ord = (bid & 7) * 112 + (bid >> 3);   // XCD chunking (bijective)
    const int n  = ord / 28;
    const int r2 = ord - n * 28;
    const int mt = r2 / 7;
    const int tg = r2 - mt * 7;

    const int tid = threadIdx.x;
    const int w = tid >> 6, l = tid & 63, lx = l & 15, lk = l >> 4;
    const int wm = w >> 1, wn = w & 1;
    const int cb = mt * 64 + wm * 16;
    const int lk16 = lk * 16;

    const uint8_t* sn = (const uint8_t*)s + (size_t)n * SIMG * 128;
    float* outn = out + (size_t)n * 512 * HW;

    auto stage = [&](int buf, int ht) {
        const int y0 = (ht * 64) / WIMG;
        const uint8_t* src = sn + (size_t)y0 * PROW * 128;
        #pragma unroll
        for (int it = 0; it < 4; ++it)
            __builtin_amdgcn_global_load_lds(GLB(src + (size_t)(it * 512 + tid) * 16),
                                             LDSP(&tile[buf][(it * 512 + tid) * 16]), 16, 0, 0);
        if (tid < 272)
            __builtin_amdgcn_global_load_lds(GLB(src + (size_t)(2048 + tid) * 16),
                                             LDSP(&tile[buf][(2048 + tid) * 16]), 16, 0, 0);
    };

    // ---- preload weight fragments into VGPRs (once per block, L2-hot) ----
    bf16x8 w1f[2], w3f[9][2];
    #pragma unroll
    for (int k0 = 0; k0 < 2; ++k0)
        w1f[k0] = *(const bf16x8*)(w1_bf + (cb + lx) * 64 + k0 * 32 + lk * 8);
    #pragma unroll
    for (int j = 0; j < 9; ++j)
        #pragma unroll
        for (int k0 = 0; k0 < 2; ++k0)
            w3f[j][k0] = *(const bf16x8*)(w3r_bf + j * 16384 + (cb + lx) * 64 + k0 * 32 + lk * 8);
    const float bias1 = b1[cb + lx];
    const float bias3 = b3[cb + lx];

    stage(0, tg * 7);
    __syncthreads();

    for (int t = 0; t < 7; ++t) {
        const int ht  = tg * 7 + t;
        const int hw0 = ht * 64;
        const int cy0 = hw0 / WIMG;
        const int cur = t & 1;
        if (t < 6) stage(cur ^ 1, ht + 1);          // flies under compute

        const int hb = hw0 + wn * 32;
        int pg[2], tb[2];
        #pragma unroll
        for (int nf = 0; nf < 2; ++nf) {
            int hw = hb + nf * 16 + lx;
            int p = hw + 59 + 2 * (hw / WIMG);
            pg[nf] = p;
            tb[nf] = (p - cy0 * PROW) * 128;
        }
        const uint8_t* tl = tile[cur];

        // ---- e1 (K=64) ----
        {
            f32x4 acc[2] = {};
            #pragma unroll
            for (int k0 = 0; k0 < 2; ++k0) {
                bf16x8 av[2];
                #pragma unroll
                for (int nf = 0; nf < 2; ++nf)
                    av[nf] = *(const bf16x8*)&tl[tb[nf] + ((lk16 + k0 * 64) ^ ((pg[nf] & 7) << 4))];
                #pragma unroll
                for (int nf = 0; nf < 2; ++nf)
                    acc[nf] = __builtin_amdgcn_mfma_f32_16x16x32_bf16(av[nf], w1f[k0], acc[nf], 0, 0, 0);
            }
            float* op = outn + (size_t)(cb + lx) * HW + hb + lk * 4;
            #pragma unroll
            for (int nf = 0; nf < 2; ++nf) {
                float4 v;
                v.x = fmaxf(acc[nf][0] + bias1, 0.0f);
                v.y = fmaxf(acc[nf][1] + bias1, 0.0f);
                v.z = fmaxf(acc[nf][2] + bias1, 0.0f);
                v.w = fmaxf(acc[nf][3] + bias1, 0.0f);
                *(float4*)(op + nf * 16) = v;
            }
        }

        // ---- e3 (9 taps x K=64, halo zero => unconditional) ----
        {
            f32x4 acc[2] = {};
            #pragma unroll
            for (int j = 0; j < 9; ++j) {
                const int doff = (j / 3 - 1) * PROW + (j % 3 - 1);
                #pragma unroll
                for (int k0 = 0; k0 < 2; ++k0) {
                    bf16x8 av[2];
                    #pragma unroll
                    for (int nf = 0; nf < 2; ++nf) {
                        int pt = pg[nf] + doff;
                        av[nf] = *(const bf16x8*)&tl[tb[nf] + doff * 128 +
                                                    ((lk16 + k0 * 64) ^ ((pt & 7) << 4))];
                    }
                    #pragma unroll
                    for (int nf = 0; nf < 2; ++nf)
                        acc[nf] = __builtin_amdgcn_mfma_f32_16x16x32_bf16(av[nf], w3f[j][k0], acc[nf], 0, 0, 0);
                }
            }
            float* op = outn + (size_t)(256 + cb + lx) * HW + hb + lk * 4;
            #pragma unroll
            for (int nf = 0; nf < 2; ++nf) {
                float4 v;
                v.x = fmaxf(acc[nf][0] + bias3, 0.0f);
                v.y = fmaxf(acc[nf][1] + bias3, 0.0f);
                v.z = fmaxf(acc[nf][2] + bias3, 0.0f);
                v.w = fmaxf(acc[nf][3] + bias3, 0.0f);
                *(float4*)(op + nf * 16) = v;
            }
        }
        __syncthreads();                            // stage(t+1) landed; buf free
    }
}

extern "C" void kernel_launch(void* const* d_in, const int* in_sizes, int n_in,
                              void* d_out, int out_size, void* d_ws, size_t ws_size,
                              hipStream_t stream) {
    const float* x   = (const float*)d_in[0];
    const float* wsq = (const float*)d_in[1];
    const float* bsq = (const float*)d_in[2];
    const float* w1  = (const float*)d_in[3];
    const float* b1  = (const float*)d_in[4];
    const float* w3  = (const float*)d_in[5];
    const float* b3  = (const float*)d_in[6];
    float* out = (float*)d_out;

    unsigned short* wsq_bf = (unsigned short*)d_ws;       // 32768 shorts
    unsigned short* w1_bf  = wsq_bf + 32768;              // 16384
    unsigned short* w3r_bf = w1_bf + 16384;               // 147456
    unsigned short* s      = w3r_bf + 147456;             // 32*3422*64 bf16 padded+swizzled

    prep_kernel<<<608, 256, 0, stream>>>(wsq, w1, w3, wsq_bf, w1_bf, w3r_bf, s);
    squeeze_kernel<<<dim3(49, 32), 256, 0, stream>>>(x, bsq, wsq_bf, s);
    expand_kernel<<<896, 512, 0, stream>>>(s, w1_bf, w3r_bf, b1, b3, out);
}